// Round 2
// baseline (572.558 us; speedup 1.0000x reference)
//
#include <hip/hip_runtime.h>

#define HF   208
#define WF   208
#define D_C  256
#define LC   10816
#define NPTS 5000
#define HW   (HF*WF)                    // 43264
#define INV_S 0.08838834764831845f      // 1/sqrt(128)
#define PAD  136                        // 128 + 8 bf16 row pad -> conflict-free ds_read_b128

typedef __bf16 bf16_t;
typedef __bf16 bf16x8 __attribute__((ext_vector_type(8)));
typedef float  f32x4  __attribute__((ext_vector_type(4)));

// ---------------------------------------------------------------------------
// Workspace layout (total 172032 B — small on purpose; no big g buffer):
//   +0      int   flag          (1 = buffers are bf16, 0 = f32)
//   +1024   float ctxs[512]     (mean * inv_s, [tensor][b][c])
//   +4096   float bias_all[128]
//   +8192   bf16  A_swz[3*16384] (B-fragment-swizzled fused corr/merge mats)
//   +106496 bf16  Dm[256*128]    (down_proj @ merge_w lower half)
// ---------------------------------------------------------------------------

// Dtype probe: low half-word of each dword, read as bf16, has |x| >= 256
// (exp field >= 135) with prob ~0.47/elem if the buffer is f32 (mantissa bits),
// and never for bf16 N(0,1) samples. 256 dwords -> P(misclassify) ~ 1e-71.
__global__ __launch_bounds__(256) void detect_kernel(
    const unsigned int* __restrict__ bits, int* __restrict__ flag) {
  __shared__ int anybig;
  if (threadIdx.x == 0) anybig = 0;
  __syncthreads();
  unsigned v = bits[threadIdx.x];
  int e = (v >> 7) & 0xFF;
  if (e >= 135) atomicOr(&anybig, 1);
  __syncthreads();
  if (threadIdx.x == 0) *flag = anybig ? 0 : 1;
}

// ---------------------------------------------------------------------------
// Kernel 1: per-(tensor,b,c) spatial means, pre-scaled by inv_s.
// ---------------------------------------------------------------------------
template <typename T>
__device__ void ctx_mean_body(const T* __restrict__ f0, const T* __restrict__ f1,
                              float* __restrict__ ctxs) {
  int id = blockIdx.x;  // 0..511
  const T* src = (id < 256 ? f0 : f1) + (size_t)(id & 255) * HW;
  float s = 0.f;
  for (int i = threadIdx.x; i < HW; i += 256) s += (float)src[i];
  for (int off = 32; off > 0; off >>= 1) s += __shfl_down(s, off, 64);
  __shared__ float part[4];
  if ((threadIdx.x & 63) == 0) part[threadIdx.x >> 6] = s;
  __syncthreads();
  if (threadIdx.x == 0)
    ctxs[id] = (part[0] + part[1] + part[2] + part[3]) * (INV_S / (float)HW);
}

__global__ __launch_bounds__(256) void ctx_mean_kernel(
    const void* f0, const void* f1, const int* __restrict__ flag,
    float* __restrict__ ctxs) {
  if (*flag) ctx_mean_body((const bf16_t*)f0, (const bf16_t*)f1, ctxs);
  else       ctx_mean_body((const float*)f0, (const float*)f1, ctxs);
}

// ---------------------------------------------------------------------------
// Kernel 2: fused weight precompute.
//  blocks 0..383  : A_mat[r][c] = sum_t corr_w[mat*128+r][t]*mg_w[t][c]
//                   (mat 0 scaled by inv_s), stored bf16 B-fragment-swizzled.
//  blocks 384..639: Dm[r][c] = sum_t dp_w[r][t]*mg_w[128+t][c]
//  block 640      : bias_all[c] = corr_b@Wm0 + dp_b@Wm1 + mg_b
// ---------------------------------------------------------------------------
template <typename T>
__device__ void prep_body(const T* __restrict__ corr_w, const T* __restrict__ corr_b,
                          const T* __restrict__ dp_w,   const T* __restrict__ dp_b,
                          const T* __restrict__ mg_w,   const T* __restrict__ mg_b,
                          bf16_t* __restrict__ A_swz, bf16_t* __restrict__ Dm,
                          float* __restrict__ bias_all) {
  int bid = blockIdx.x;
  int c = threadIdx.x;
  if (bid < 384) {
    int mat = bid >> 7, r = bid & 127;
    float acc = 0.f;
    for (int t = 0; t < 128; ++t)
      acc += (float)corr_w[(mat * 128 + r) * 128 + t] * (float)mg_w[t * 128 + c];
    if (mat == 0) acc *= INV_S;
    // B-fragment swizzle for mfma_f32_16x16x32_bf16: elem (k=r, n=c) ->
    // lane = ((k&31)>>3)*16 + (n&15), j = k&7, tiles (nt=n>>4, ks=k>>5)
    int ks = r >> 5, quad = (r & 31) >> 3, jj = r & 7;
    int nt = c >> 4, lr = c & 15;
    A_swz[mat * 16384 + (((nt * 4 + ks) * 64) + quad * 16 + lr) * 8 + jj] = (bf16_t)acc;
  } else if (bid < 640) {
    int r = bid - 384;
    float acc = 0.f;
    for (int t = 0; t < 128; ++t)
      acc += (float)dp_w[r * 128 + t] * (float)mg_w[(128 + t) * 128 + c];
    Dm[r * 128 + c] = (bf16_t)acc;
  } else {
    float acc = (float)mg_b[c];
    for (int t = 0; t < 128; ++t) {
      acc += (float)corr_b[t] * (float)mg_w[t * 128 + c];
      acc += (float)dp_b[t]   * (float)mg_w[(128 + t) * 128 + c];
    }
    bias_all[c] = acc;
  }
}

__global__ __launch_bounds__(128) void prep_kernel(
    const void* corr_w, const void* corr_b, const void* dp_w, const void* dp_b,
    const void* mg_w, const void* mg_b, const int* __restrict__ flag,
    bf16_t* __restrict__ A_swz, bf16_t* __restrict__ Dm,
    float* __restrict__ bias_all) {
  if (*flag)
    prep_body((const bf16_t*)corr_w, (const bf16_t*)corr_b, (const bf16_t*)dp_w,
              (const bf16_t*)dp_b, (const bf16_t*)mg_w, (const bf16_t*)mg_b,
              A_swz, Dm, bias_all);
  else
    prep_body((const float*)corr_w, (const float*)corr_b, (const float*)dp_w,
              (const float*)dp_b, (const float*)mg_w, (const float*)mg_b,
              A_swz, Dm, bias_all);
}

// ---------------------------------------------------------------------------
// Kernel 3: main — one block per match n. Inline g = fc@Dm, gather patches
// into LDS, 5 shared (32x128)@(128x128) MFMA matmuls, epilogue adds g+bias.
// ---------------------------------------------------------------------------
template <typename T>
__device__ void main_body(
    const T* __restrict__ f0, const T* __restrict__ f1,
    const T* __restrict__ fc0, const T* __restrict__ fc1,
    const int* __restrict__ b_ids, const int* __restrict__ i_ids,
    const int* __restrict__ j_ids, const int* __restrict__ w0c_p,
    const int* __restrict__ w1c_p, const float* __restrict__ ctxs,
    const float* __restrict__ bias_all, const bf16_t* __restrict__ A_swz,
    const bf16_t* __restrict__ Dm, T* __restrict__ out) {
  __shared__ __align__(16) bf16_t sV[3][32][PAD];  // 0: p0*p1, 1: p0*cs1, 2: p1*cs0
  __shared__ float sg[2][128];

  int n = blockIdx.x;
  int tid = threadIdx.x;
  int b = b_ids[n], ii = i_ids[n], jj = j_ids[n];
  int w0c = w0c_p[0], w1c = w1c_p[0];
  int x0 = min((ii % w0c) * 2, WF - 1), y0 = min((ii / w0c) * 2, HF - 1);
  int x1 = min((jj % w1c) * 2, WF - 1), y1 = min((jj / w1c) * 2, HF - 1);

  // ---- phase 1a: gather patches ----
  int c = tid & 127, kh = tid >> 7;
  float cs0 = ctxs[b * 128 + c];          // mean(f0)*inv_s
  float cs1 = ctxs[256 + b * 128 + c];    // mean(f1)*inv_s
  const T* f0b = f0 + (size_t)(b * 128 + c) * HW;
  const T* f1b = f1 + (size_t)(b * 128 + c) * HW;
  for (int k = kh; k < 32; k += 2) {
    float p0 = 0.f, p1 = 0.f;
    if (k < 25) {
      int dy = k / 5 - 2, dx = k % 5 - 2;
      int ya = y0 + dy, xa = x0 + dx;
      if (ya >= 0 && ya < HF && xa >= 0 && xa < WF) p0 = (float)f0b[ya * WF + xa];
      int yb = y1 + dy, xb = x1 + dx;
      if (yb >= 0 && yb < HF && xb >= 0 && xb < WF) p1 = (float)f1b[yb * WF + xb];
    }
    sV[0][k][c] = (bf16_t)(p0 * p1);
    sV[1][k][c] = (bf16_t)(p0 * cs1);
    sV[2][k][c] = (bf16_t)(p1 * cs0);
  }

  // ---- phase 1b: inline g = fc_row @ Dm (h=0 -> out0 via fc0[b,ii]) ----
  {
    int h = kh, col = c;
    const T* fcrow = h ? fc1 + ((size_t)b * LC + jj) * D_C
                       : fc0 + ((size_t)b * LC + ii) * D_C;
    float acc = 0.f;
#pragma unroll 8
    for (int t = 0; t < D_C; ++t)
      acc += (float)fcrow[t] * (float)Dm[t * 128 + col];
    sg[h][col] = acc;
  }
  __syncthreads();

  // ---- phase 2: MFMA ----
  int w = tid >> 6, lane = tid & 63, quad = lane >> 4, lr = lane & 15;
  f32x4 accP[2][2] = {};   // vp@A0 (shared by both outputs)
  f32x4 acc01[2][2] = {};  // v0@A1 + v1@A2  (-> out0)
  f32x4 acc10[2][2] = {};  // v1@A1 + v0@A2  (-> out1)

#pragma unroll
  for (int ks = 0; ks < 4; ++ks) {
    bf16x8 va[2][3];
#pragma unroll
    for (int mt = 0; mt < 2; ++mt)
#pragma unroll
      for (int m = 0; m < 3; ++m)
        va[mt][m] = *(const bf16x8*)&sV[m][mt * 16 + lr][ks * 32 + quad * 8];
    bf16x8 vb[3][2];
#pragma unroll
    for (int m = 0; m < 3; ++m)
#pragma unroll
      for (int ntl = 0; ntl < 2; ++ntl) {
        int nt = w * 2 + ntl;
        vb[m][ntl] = *(const bf16x8*)(A_swz + m * 16384 + (((nt * 4 + ks) * 64) + lane) * 8);
      }
#pragma unroll
    for (int mt = 0; mt < 2; ++mt)
#pragma unroll
      for (int ntl = 0; ntl < 2; ++ntl) {
        accP[mt][ntl]  = __builtin_amdgcn_mfma_f32_16x16x32_bf16(va[mt][0], vb[0][ntl], accP[mt][ntl], 0, 0, 0);
        acc01[mt][ntl] = __builtin_amdgcn_mfma_f32_16x16x32_bf16(va[mt][1], vb[1][ntl], acc01[mt][ntl], 0, 0, 0);
        acc01[mt][ntl] = __builtin_amdgcn_mfma_f32_16x16x32_bf16(va[mt][2], vb[2][ntl], acc01[mt][ntl], 0, 0, 0);
        acc10[mt][ntl] = __builtin_amdgcn_mfma_f32_16x16x32_bf16(va[mt][2], vb[1][ntl], acc10[mt][ntl], 0, 0, 0);
        acc10[mt][ntl] = __builtin_amdgcn_mfma_f32_16x16x32_bf16(va[mt][1], vb[2][ntl], acc10[mt][ntl], 0, 0, 0);
      }
  }

  // ---- epilogue (C/D layout: col = lane&15 (+tiles), row = quad*4+reg) ----
#pragma unroll
  for (int ntl = 0; ntl < 2; ++ntl) {
    int col = w * 32 + ntl * 16 + lr;
    float bg = bias_all[col];
    float g0 = sg[0][col] + bg;
    float g1 = sg[1][col] + bg;
#pragma unroll
    for (int mt = 0; mt < 2; ++mt)
#pragma unroll
      for (int rg = 0; rg < 4; ++rg) {
        int row = mt * 16 + quad * 4 + rg;
        if (row < 25) {
          size_t o = ((size_t)n * 25 + row) * 128 + col;
          out[o] = (T)(accP[mt][ntl][rg] + acc01[mt][ntl][rg] + g0);
          out[(size_t)NPTS * 25 * 128 + o] = (T)(accP[mt][ntl][rg] + acc10[mt][ntl][rg] + g1);
        }
      }
  }
}

__global__ __launch_bounds__(256, 2) void main_kernel(
    const void* f0, const void* f1, const void* fc0, const void* fc1,
    const int* __restrict__ b_ids, const int* __restrict__ i_ids,
    const int* __restrict__ j_ids, const int* __restrict__ w0c_p,
    const int* __restrict__ w1c_p, const int* __restrict__ flag,
    const float* __restrict__ ctxs, const float* __restrict__ bias_all,
    const bf16_t* __restrict__ A_swz, const bf16_t* __restrict__ Dm, void* out) {
  if (*flag)
    main_body((const bf16_t*)f0, (const bf16_t*)f1, (const bf16_t*)fc0,
              (const bf16_t*)fc1, b_ids, i_ids, j_ids, w0c_p, w1c_p, ctxs,
              bias_all, A_swz, Dm, (bf16_t*)out);
  else
    main_body((const float*)f0, (const float*)f1, (const float*)fc0,
              (const float*)fc1, b_ids, i_ids, j_ids, w0c_p, w1c_p, ctxs,
              bias_all, A_swz, Dm, (float*)out);
}

// ---------------------------------------------------------------------------
extern "C" void kernel_launch(void* const* d_in, const int* in_sizes, int n_in,
                              void* d_out, int out_size, void* d_ws, size_t ws_size,
                              hipStream_t stream) {
  const void* f0     = d_in[0];
  const void* f1     = d_in[1];
  const void* fc0    = d_in[2];
  const void* fc1    = d_in[3];
  const void* corr_w = d_in[4];
  const void* corr_b = d_in[5];
  const void* dp_w   = d_in[6];
  const void* dp_b   = d_in[7];
  const void* mg_w   = d_in[8];
  const void* mg_b   = d_in[9];
  const int* b_ids   = (const int*)d_in[10];
  const int* i_ids   = (const int*)d_in[11];
  const int* j_ids   = (const int*)d_in[12];
  const int* w0c     = (const int*)d_in[13];
  const int* w1c     = (const int*)d_in[14];

  char* ws = (char*)d_ws;
  int*    flag     = (int*)ws;
  float*  ctxs     = (float*)(ws + 1024);
  float*  bias_all = (float*)(ws + 4096);
  bf16_t* A_swz    = (bf16_t*)(ws + 8192);
  bf16_t* Dm       = (bf16_t*)(ws + 106496);

  detect_kernel<<<1, 256, 0, stream>>>((const unsigned int*)f0, flag);
  ctx_mean_kernel<<<512, 256, 0, stream>>>(f0, f1, flag, ctxs);
  prep_kernel<<<641, 128, 0, stream>>>(corr_w, corr_b, dp_w, dp_b, mg_w, mg_b,
                                       flag, A_swz, Dm, bias_all);
  main_kernel<<<NPTS, 256, 0, stream>>>(f0, f1, fc0, fc1, b_ids, i_ids, j_ids,
                                        w0c, w1c, flag, ctxs, bias_all, A_swz,
                                        Dm, d_out);
}

// Round 3
// 440.911 us; speedup vs baseline: 1.2986x; 1.2986x over previous
//
#include <hip/hip_runtime.h>

#define HF   208
#define WF   208
#define D_C  256
#define LC   10816
#define NPTS 5000
#define HW   (HF*WF)                    // 43264
#define INV_S 0.08838834764831845f      // 1/sqrt(128)
#define PAD  136                        // bf16 row pad for sV

typedef __bf16 bf16_t;
typedef __bf16 bf16x8 __attribute__((ext_vector_type(8)));
typedef float  f32x4  __attribute__((ext_vector_type(4)));

// Workspace layout:
//   +0        float ctxs[512]        (mean * inv_s, [tensor][b][c])
//   +4096     float bias_all[128]
//   +8192     bf16  A_swz[3*16384]   (B-fragment-swizzled fused mats)
//   +106496   bf16  Dm[256*128]
//   +172032   bf16  ftr[2][2][HW][128]  (44.3 MB transposed features)
#define FTR_OFF   172032
#define FTR_BYTES ((size_t)2*2*HW*128*2)

// ---------------------------------------------------------------------------
// Kernel 0: transpose (B,C,H,W) f32 -> (t,b,HW,C) bf16.  676 hw-tiles of 64.
// ---------------------------------------------------------------------------
__global__ __launch_bounds__(256) void transpose_kernel(
    const float* __restrict__ f0, const float* __restrict__ f1,
    bf16_t* __restrict__ ftr) {
  __shared__ float tile[64][129];      // [w][c], +1 pad -> store phase bank-free
  int bid = blockIdx.x;                // 0..2703
  int tb = bid / 676;                  // t*2+b
  int hw0 = (bid % 676) * 64;
  const float* src = (tb < 2 ? f0 : f1) + (size_t)((tb & 1) * 128) * HW;
  int w = threadIdx.x & 63, c0 = threadIdx.x >> 6;
  for (int c = c0; c < 128; c += 4)
    tile[w][c] = src[(size_t)c * HW + hw0 + w];
  __syncthreads();
  bf16_t* dst = ftr + ((size_t)tb * HW + hw0) * 128;
  int sub = threadIdx.x & 15, cb = sub * 8;
  for (int p = (threadIdx.x >> 4); p < 64; p += 16) {
    bf16x8 v;
#pragma unroll
    for (int j = 0; j < 8; ++j) v[j] = (bf16_t)tile[p][cb + j];
    *(bf16x8*)(dst + (size_t)p * 128 + cb) = v;   // 16 lanes x 16B = 256B/pos
  }
}

// ---------------------------------------------------------------------------
// Kernel 1: per-(tensor,b,c) spatial means, pre-scaled by inv_s.
// ---------------------------------------------------------------------------
__global__ __launch_bounds__(256) void ctx_mean_kernel(
    const float* __restrict__ f0, const float* __restrict__ f1,
    float* __restrict__ ctxs) {
  int id = blockIdx.x;  // 0..511
  const float* src = (id < 256 ? f0 : f1) + (size_t)(id & 255) * HW;
  float s = 0.f;
  for (int i = threadIdx.x; i < HW; i += 256) s += src[i];
  for (int off = 32; off > 0; off >>= 1) s += __shfl_down(s, off, 64);
  __shared__ float part[4];
  if ((threadIdx.x & 63) == 0) part[threadIdx.x >> 6] = s;
  __syncthreads();
  if (threadIdx.x == 0)
    ctxs[id] = (part[0] + part[1] + part[2] + part[3]) * (INV_S / (float)HW);
}

// ---------------------------------------------------------------------------
// Kernel 2: fused weight precompute (f32 weights).
// ---------------------------------------------------------------------------
__global__ __launch_bounds__(128) void prep_kernel(
    const float* __restrict__ corr_w, const float* __restrict__ corr_b,
    const float* __restrict__ dp_w,   const float* __restrict__ dp_b,
    const float* __restrict__ mg_w,   const float* __restrict__ mg_b,
    bf16_t* __restrict__ A_swz, bf16_t* __restrict__ Dm,
    float* __restrict__ bias_all) {
  int bid = blockIdx.x;
  int c = threadIdx.x;
  if (bid < 384) {
    int mat = bid >> 7, r = bid & 127;
    float acc = 0.f;
    for (int t = 0; t < 128; ++t)
      acc += corr_w[(mat * 128 + r) * 128 + t] * mg_w[t * 128 + c];
    if (mat == 0) acc *= INV_S;
    // B-fragment swizzle (mfma_f32_16x16x32_bf16): (k=r,n=c) ->
    // lane=((k&31)>>3)*16+(n&15), j=k&7, tiles (nt=n>>4, ks=k>>5)
    int ks = r >> 5, quad = (r & 31) >> 3, jj = r & 7;
    int nt = c >> 4, lr = c & 15;
    A_swz[mat * 16384 + (((nt * 4 + ks) * 64) + quad * 16 + lr) * 8 + jj] = (bf16_t)acc;
  } else if (bid < 640) {
    int r = bid - 384;
    float acc = 0.f;
    for (int t = 0; t < 128; ++t)
      acc += dp_w[r * 128 + t] * mg_w[(128 + t) * 128 + c];
    Dm[r * 128 + c] = (bf16_t)acc;
  } else {
    float acc = mg_b[c];
    for (int t = 0; t < 128; ++t) {
      acc += corr_b[t] * mg_w[t * 128 + c];
      acc += dp_b[t]   * mg_w[(128 + t) * 128 + c];
    }
    bias_all[c] = acc;
  }
}

// ---------------------------------------------------------------------------
// Kernel 3: main — one block per match n.
// ---------------------------------------------------------------------------
__global__ __launch_bounds__(256, 4) void main_kernel(
    const float* __restrict__ f0, const float* __restrict__ f1,
    const float* __restrict__ fc0, const float* __restrict__ fc1,
    const int* __restrict__ b_ids, const int* __restrict__ i_ids,
    const int* __restrict__ j_ids, const int* __restrict__ w0c_p,
    const int* __restrict__ w1c_p, const float* __restrict__ ctxs,
    const float* __restrict__ bias_all, const bf16_t* __restrict__ A_swz,
    const bf16_t* __restrict__ Dm, const bf16_t* __restrict__ ftr,
    int use_ftr, float* __restrict__ out) {
  __shared__ __align__(16) bf16_t sV[3][32][PAD];  // 0: p0*p1, 1: p0*cs1, 2: p1*cs0
  __shared__ float sg[2][128];

  int n = blockIdx.x;
  int tid = threadIdx.x;
  int b = b_ids[n], ii = i_ids[n], jj = j_ids[n];
  int w0c = w0c_p[0], w1c = w1c_p[0];
  int x0 = min((ii % w0c) * 2, WF - 1), y0 = min((ii / w0c) * 2, HF - 1);
  int x1 = min((jj % w1c) * 2, WF - 1), y1 = min((jj / w1c) * 2, HF - 1);

  if (use_ftr) {
    // ---- gather from transposed bf16 layout: 8 lanes per patch position ----
    int grp = tid >> 3, e = tid & 7;
    const bf16_t* base0 = ftr + (size_t)b * HW * 128;
    const bf16_t* base1 = ftr + (size_t)(2 + b) * HW * 128;
    if (grp < 25) {
      int dy = grp / 5 - 2, dx = grp % 5 - 2;
      int ya = y0 + dy, xa = x0 + dx;
      int yb = y1 + dy, xb = x1 + dx;
      bool v0 = (ya >= 0 && ya < HF && xa >= 0 && xa < WF);
      bool v1 = (yb >= 0 && yb < HF && xb >= 0 && xb < WF);
      const bf16_t* r0 = base0 + ((size_t)(v0 ? ya * WF + xa : 0)) * 128;
      const bf16_t* r1 = base1 + ((size_t)(v1 ? yb * WF + xb : 0)) * 128;
#pragma unroll
      for (int h = 0; h < 2; ++h) {
        int cb = h * 64 + e * 8;
        bf16x8 a0 = *(const bf16x8*)(r0 + cb);
        bf16x8 a1 = *(const bf16x8*)(r1 + cb);
        f32x4 cs0a = *(const f32x4*)&ctxs[b * 128 + cb];
        f32x4 cs0b = *(const f32x4*)&ctxs[b * 128 + cb + 4];
        f32x4 cs1a = *(const f32x4*)&ctxs[256 + b * 128 + cb];
        f32x4 cs1b = *(const f32x4*)&ctxs[256 + b * 128 + cb + 4];
        bf16x8 oP, o1, o2;
#pragma unroll
        for (int j = 0; j < 8; ++j) {
          float p0 = v0 ? (float)a0[j] : 0.f;
          float p1 = v1 ? (float)a1[j] : 0.f;
          float c0f = j < 4 ? cs0a[j & 3] : cs0b[j & 3];
          float c1f = j < 4 ? cs1a[j & 3] : cs1b[j & 3];
          oP[j] = (bf16_t)(p0 * p1);
          o1[j] = (bf16_t)(p0 * c1f);
          o2[j] = (bf16_t)(p1 * c0f);
        }
        *(bf16x8*)&sV[0][grp][cb] = oP;
        *(bf16x8*)&sV[1][grp][cb] = o1;
        *(bf16x8*)&sV[2][grp][cb] = o2;
      }
    } else {
      bf16x8 z = {};
#pragma unroll
      for (int h = 0; h < 2; ++h) {
        int cb = h * 64 + e * 8;
        *(bf16x8*)&sV[0][grp][cb] = z;
        *(bf16x8*)&sV[1][grp][cb] = z;
        *(bf16x8*)&sV[2][grp][cb] = z;
      }
    }
  } else {
    // ---- fallback: strided gather from original f32 layout ----
    int c = tid & 127, kh = tid >> 7;
    float cs0 = ctxs[b * 128 + c];
    float cs1 = ctxs[256 + b * 128 + c];
    const float* f0b = f0 + (size_t)(b * 128 + c) * HW;
    const float* f1b = f1 + (size_t)(b * 128 + c) * HW;
    for (int k = kh; k < 32; k += 2) {
      float p0 = 0.f, p1 = 0.f;
      if (k < 25) {
        int dy = k / 5 - 2, dx = k % 5 - 2;
        int ya = y0 + dy, xa = x0 + dx;
        if (ya >= 0 && ya < HF && xa >= 0 && xa < WF) p0 = f0b[ya * WF + xa];
        int yb = y1 + dy, xb = x1 + dx;
        if (yb >= 0 && yb < HF && xb >= 0 && xb < WF) p1 = f1b[yb * WF + xb];
      }
      sV[0][k][c] = (bf16_t)(p0 * p1);
      sV[1][k][c] = (bf16_t)(p0 * cs1);
      sV[2][k][c] = (bf16_t)(p1 * cs0);
    }
  }

  // ---- inline g = fc_row @ Dm ----
  {
    int h = tid >> 7, col = tid & 127;
    const float* fcrow = h ? fc1 + ((size_t)b * LC + jj) * D_C
                           : fc0 + ((size_t)b * LC + ii) * D_C;
    float acc = 0.f;
#pragma unroll 8
    for (int t = 0; t < D_C; ++t)
      acc += fcrow[t] * (float)Dm[t * 128 + col];
    sg[h][col] = acc;
  }
  __syncthreads();

  // ---- MFMA phase ----
  int w = tid >> 6, lane = tid & 63, quad = lane >> 4, lr = lane & 15;
  f32x4 accP[2][2] = {};   // vp@A0 (shared by both outputs)
  f32x4 acc01[2][2] = {};  // v0@A1 + v1@A2  (-> out0)
  f32x4 acc10[2][2] = {};  // v1@A1 + v0@A2  (-> out1)

#pragma unroll
  for (int ks = 0; ks < 4; ++ks) {
    bf16x8 va[2][3];
#pragma unroll
    for (int mt = 0; mt < 2; ++mt)
#pragma unroll
      for (int m = 0; m < 3; ++m)
        va[mt][m] = *(const bf16x8*)&sV[m][mt * 16 + lr][ks * 32 + quad * 8];
    bf16x8 vb[3][2];
#pragma unroll
    for (int m = 0; m < 3; ++m)
#pragma unroll
      for (int ntl = 0; ntl < 2; ++ntl) {
        int nt = w * 2 + ntl;
        vb[m][ntl] = *(const bf16x8*)(A_swz + m * 16384 + (((nt * 4 + ks) * 64) + lane) * 8);
      }
#pragma unroll
    for (int mt = 0; mt < 2; ++mt)
#pragma unroll
      for (int ntl = 0; ntl < 2; ++ntl) {
        accP[mt][ntl]  = __builtin_amdgcn_mfma_f32_16x16x32_bf16(va[mt][0], vb[0][ntl], accP[mt][ntl], 0, 0, 0);
        acc01[mt][ntl] = __builtin_amdgcn_mfma_f32_16x16x32_bf16(va[mt][1], vb[1][ntl], acc01[mt][ntl], 0, 0, 0);
        acc01[mt][ntl] = __builtin_amdgcn_mfma_f32_16x16x32_bf16(va[mt][2], vb[2][ntl], acc01[mt][ntl], 0, 0, 0);
        acc10[mt][ntl] = __builtin_amdgcn_mfma_f32_16x16x32_bf16(va[mt][2], vb[1][ntl], acc10[mt][ntl], 0, 0, 0);
        acc10[mt][ntl] = __builtin_amdgcn_mfma_f32_16x16x32_bf16(va[mt][1], vb[2][ntl], acc10[mt][ntl], 0, 0, 0);
      }
  }

  // ---- epilogue (C/D: col = lane&15 (+tiles), row = quad*4+reg) ----
#pragma unroll
  for (int ntl = 0; ntl < 2; ++ntl) {
    int col = w * 32 + ntl * 16 + lr;
    float bg = bias_all[col];
    float g0 = sg[0][col] + bg;
    float g1 = sg[1][col] + bg;
#pragma unroll
    for (int mt = 0; mt < 2; ++mt)
#pragma unroll
      for (int rg = 0; rg < 4; ++rg) {
        int row = mt * 16 + quad * 4 + rg;
        if (row < 25) {
          size_t o = ((size_t)n * 25 + row) * 128 + col;
          out[o] = accP[mt][ntl][rg] + acc01[mt][ntl][rg] + g0;
          out[(size_t)NPTS * 25 * 128 + o] = accP[mt][ntl][rg] + acc10[mt][ntl][rg] + g1;
        }
      }
  }
}

// ---------------------------------------------------------------------------
extern "C" void kernel_launch(void* const* d_in, const int* in_sizes, int n_in,
                              void* d_out, int out_size, void* d_ws, size_t ws_size,
                              hipStream_t stream) {
  const float* f0     = (const float*)d_in[0];
  const float* f1     = (const float*)d_in[1];
  const float* fc0    = (const float*)d_in[2];
  const float* fc1    = (const float*)d_in[3];
  const float* corr_w = (const float*)d_in[4];
  const float* corr_b = (const float*)d_in[5];
  const float* dp_w   = (const float*)d_in[6];
  const float* dp_b   = (const float*)d_in[7];
  const float* mg_w   = (const float*)d_in[8];
  const float* mg_b   = (const float*)d_in[9];
  const int* b_ids    = (const int*)d_in[10];
  const int* i_ids    = (const int*)d_in[11];
  const int* j_ids    = (const int*)d_in[12];
  const int* w0c      = (const int*)d_in[13];
  const int* w1c      = (const int*)d_in[14];

  char* ws = (char*)d_ws;
  float*  ctxs     = (float*)(ws);
  float*  bias_all = (float*)(ws + 4096);
  bf16_t* A_swz    = (bf16_t*)(ws + 8192);
  bf16_t* Dm       = (bf16_t*)(ws + 106496);
  bf16_t* ftr      = (bf16_t*)(ws + FTR_OFF);
  int use_ftr = (ws_size >= FTR_OFF + FTR_BYTES) ? 1 : 0;

  ctx_mean_kernel<<<512, 256, 0, stream>>>(f0, f1, ctxs);
  prep_kernel<<<641, 128, 0, stream>>>(corr_w, corr_b, dp_w, dp_b, mg_w, mg_b,
                                       A_swz, Dm, bias_all);
  if (use_ftr)
    transpose_kernel<<<2704, 256, 0, stream>>>(f0, f1, ftr);
  main_kernel<<<NPTS, 256, 0, stream>>>(f0, f1, fc0, fc1, b_ids, i_ids, j_ids,
                                        w0c, w1c, ctxs, bias_all, A_swz, Dm,
                                        ftr, use_ftr, (float*)d_out);
}

// Round 4
// 357.560 us; speedup vs baseline: 1.6013x; 1.2331x over previous
//
#include <hip/hip_runtime.h>

#define HF   208
#define WF   208
#define D_C  256
#define LC   10816
#define NPTS 5000
#define HW   (HF*WF)                    // 43264
#define INV_S 0.08838834764831845f      // 1/sqrt(128)
#define PAD  136                        // bf16 row pad for sV

typedef __bf16 bf16_t;
typedef __bf16 bf16x8 __attribute__((ext_vector_type(8)));
typedef float  f32x4  __attribute__((ext_vector_type(4)));

// Workspace layout:
//   +0        float ctxs[512]       raw channel sums (atomic), scaled in main
//   +4096     float bias_all[128]
//   +8192     bf16  A_swz[3*16384]  B-fragment-swizzled fused mats
//   +106496   bf16  Dm[256*128]
//   +172032   bf16  ftr[2][2][HW][128]   44.30 MB transposed features
//   +44474368 float g[10000][128]        5.12 MB  (fc@Dm + bias, per row)
#define FTR_OFF   172032
#define FTR_BYTES ((size_t)2*2*HW*128*2)
#define G_OFF     (FTR_OFF + FTR_BYTES)
#define G_BYTES   ((size_t)2*NPTS*128*4)

// ---------------------------------------------------------------------------
// Kernel 0: transpose (B,C,H,W) f32 -> (t,b,HW,C) bf16, + channel sums.
// ---------------------------------------------------------------------------
__global__ __launch_bounds__(256) void transpose_kernel(
    const float* __restrict__ f0, const float* __restrict__ f1,
    bf16_t* __restrict__ ftr, float* __restrict__ ctxs) {
  __shared__ float tile[64][129];
  __shared__ float cred[128];
  int bid = blockIdx.x;                // 0..2703
  int tb = bid / 676;                  // t*2+b
  int hw0 = (bid % 676) * 64;
  const float* src = (tb < 2 ? f0 : f1) + (size_t)((tb & 1) * 128) * HW;
  int tid = threadIdx.x;
  if (tid < 128) cred[tid] = 0.f;
  // read: float4 along w
  int w4 = (tid & 15) * 4, cr = tid >> 4;
  for (int c = cr; c < 128; c += 16) {
    f32x4 v = *(const f32x4*)&src[(size_t)c * HW + hw0 + w4];
#pragma unroll
    for (int j = 0; j < 4; ++j) tile[w4 + j][c] = v[j];
  }
  __syncthreads();
  // store: bf16x8 along c, accumulate channel sums on the way
  bf16_t* dst = ftr + ((size_t)tb * HW + hw0) * 128;
  int cb = (tid & 15) * 8;
  float sums8[8] = {0, 0, 0, 0, 0, 0, 0, 0};
  for (int p = (tid >> 4); p < 64; p += 16) {
    bf16x8 v;
#pragma unroll
    for (int j = 0; j < 8; ++j) {
      float x = tile[p][cb + j];
      sums8[j] += x;
      v[j] = (bf16_t)x;
    }
    *(bf16x8*)(dst + (size_t)p * 128 + cb) = v;
  }
  int lane = tid & 63;
#pragma unroll
  for (int j = 0; j < 8; ++j) {
    float s = sums8[j];
    s += __shfl_down(s, 32, 64);
    s += __shfl_down(s, 16, 64);
    if (lane < 16) atomicAdd(&cred[cb + j], s);
  }
  __syncthreads();
  if (tid < 128) atomicAdd(&ctxs[tb * 128 + tid], cred[tid]);
}

// ---------------------------------------------------------------------------
// Kernel 1: fused weight precompute (f32 weights).
// ---------------------------------------------------------------------------
__global__ __launch_bounds__(128) void prep_kernel(
    const float* __restrict__ corr_w, const float* __restrict__ corr_b,
    const float* __restrict__ dp_w,   const float* __restrict__ dp_b,
    const float* __restrict__ mg_w,   const float* __restrict__ mg_b,
    bf16_t* __restrict__ A_swz, bf16_t* __restrict__ Dm,
    float* __restrict__ bias_all) {
  int bid = blockIdx.x;
  int c = threadIdx.x;
  if (bid < 384) {
    int mat = bid >> 7, r = bid & 127;
    float acc = 0.f;
    for (int t = 0; t < 128; ++t)
      acc += corr_w[(mat * 128 + r) * 128 + t] * mg_w[t * 128 + c];
    if (mat == 0) acc *= INV_S;
    // B-fragment swizzle (mfma_f32_16x16x32_bf16): (k=r,n=c) ->
    // lane=((k&31)>>3)*16+(n&15), j=k&7, tiles (nt=n>>4, ks=k>>5)
    int ks = r >> 5, quad = (r & 31) >> 3, jj = r & 7;
    int nt = c >> 4, lr = c & 15;
    A_swz[mat * 16384 + (((nt * 4 + ks) * 64) + quad * 16 + lr) * 8 + jj] = (bf16_t)acc;
  } else if (bid < 640) {
    int r = bid - 384;
    float acc = 0.f;
    for (int t = 0; t < 128; ++t)
      acc += dp_w[r * 128 + t] * mg_w[(128 + t) * 128 + c];
    Dm[r * 128 + c] = (bf16_t)acc;
  } else {
    float acc = mg_b[c];
    for (int t = 0; t < 128; ++t) {
      acc += corr_b[t] * mg_w[t * 128 + c];
      acc += dp_b[t]   * mg_w[(128 + t) * 128 + c];
    }
    bias_all[c] = acc;
  }
}

// ---------------------------------------------------------------------------
// Kernel 2: g[r][c] = fc_row(r) @ Dm + bias_all[c]   (2N x 128 f32)
// ---------------------------------------------------------------------------
__global__ __launch_bounds__(128) void g_kernel(
    const float* __restrict__ fc0, const float* __restrict__ fc1,
    const int* __restrict__ b_ids, const int* __restrict__ i_ids,
    const int* __restrict__ j_ids, const bf16_t* __restrict__ Dm,
    const float* __restrict__ bias_all, float* __restrict__ g) {
  __shared__ float s_src[16][D_C];
  int r0 = blockIdx.x * 16;
  int tid = threadIdx.x;
  for (int u = tid; u < 16 * D_C; u += 128) {
    int rr = u >> 8, t = u & 255;
    int r = r0 + rr;
    const float* src;
    int b, idx;
    if (r < NPTS) { b = b_ids[r]; idx = i_ids[r]; src = fc0; }
    else          { b = b_ids[r - NPTS]; idx = j_ids[r - NPTS]; src = fc1; }
    s_src[rr][t] = src[((size_t)b * LC + idx) * D_C + t];
  }
  __syncthreads();
  float acc[16];
#pragma unroll
  for (int rr = 0; rr < 16; ++rr) acc[rr] = 0.f;
  for (int t = 0; t < D_C; ++t) {
    float d = (float)Dm[t * 128 + tid];
#pragma unroll
    for (int rr = 0; rr < 16; ++rr) acc[rr] += s_src[rr][t] * d;
  }
  float bv = bias_all[tid];
#pragma unroll
  for (int rr = 0; rr < 16; ++rr) g[(size_t)(r0 + rr) * 128 + tid] = acc[rr] + bv;
}

// ---------------------------------------------------------------------------
// Kernel 3: main — one block per match n. Gather -> MFMA -> LDS-staged
// coalesced nontemporal output.
// ---------------------------------------------------------------------------
__global__ __launch_bounds__(256, 6) void main_kernel(
    const bf16_t* __restrict__ ftr,
    const int* __restrict__ b_ids, const int* __restrict__ i_ids,
    const int* __restrict__ j_ids, const int* __restrict__ w0c_p,
    const int* __restrict__ w1c_p, const float* __restrict__ ctxs,
    const bf16_t* __restrict__ A_swz, const float* __restrict__ g,
    float* __restrict__ out) {
  __shared__ __align__(16) union {
    bf16_t sV[3][32][PAD];     // 0: p0*p1, 1: p0*cs1, 2: p1*cs0
    float  so[2][25][132];     // f32 output staging (aliased after MFMA)
  } sm;

  int n = blockIdx.x;
  int tid = threadIdx.x;
  int b = b_ids[n], ii = i_ids[n], jj = j_ids[n];
  int w0c = w0c_p[0], w1c = w1c_p[0];
  int x0 = min((ii % w0c) * 2, WF - 1), y0 = min((ii / w0c) * 2, HF - 1);
  int x1 = min((jj % w1c) * 2, WF - 1), y1 = min((jj / w1c) * 2, HF - 1);

  // ---- gather: 8 lanes per patch position (rows 25..31 left stale: their
  //      MFMA output rows are discarded by the row<25 guard) ----
  int grp = tid >> 3, e = tid & 7;
  if (grp < 25) {
    const bf16_t* base0 = ftr + (size_t)b * HW * 128;
    const bf16_t* base1 = ftr + (size_t)(2 + b) * HW * 128;
    int dy = grp / 5 - 2, dx = grp % 5 - 2;
    int ya = y0 + dy, xa = x0 + dx;
    int yb = y1 + dy, xb = x1 + dx;
    bool v0 = (ya >= 0 && ya < HF && xa >= 0 && xa < WF);
    bool v1 = (yb >= 0 && yb < HF && xb >= 0 && xb < WF);
    const bf16_t* r0 = base0 + ((size_t)(v0 ? ya * WF + xa : 0)) * 128;
    const bf16_t* r1 = base1 + ((size_t)(v1 ? yb * WF + xb : 0)) * 128;
    const float ksc = INV_S / (float)HW;   // ctxs holds raw sums
#pragma unroll
    for (int h = 0; h < 2; ++h) {
      int cb = h * 64 + e * 8;
      bf16x8 a0 = *(const bf16x8*)(r0 + cb);
      bf16x8 a1 = *(const bf16x8*)(r1 + cb);
      f32x4 cs0a = *(const f32x4*)&ctxs[b * 128 + cb];
      f32x4 cs0b = *(const f32x4*)&ctxs[b * 128 + cb + 4];
      f32x4 cs1a = *(const f32x4*)&ctxs[256 + b * 128 + cb];
      f32x4 cs1b = *(const f32x4*)&ctxs[256 + b * 128 + cb + 4];
      bf16x8 oP, o1, o2;
#pragma unroll
      for (int j = 0; j < 8; ++j) {
        float p0 = v0 ? (float)a0[j] : 0.f;
        float p1 = v1 ? (float)a1[j] : 0.f;
        float c0f = (j < 4 ? cs0a[j & 3] : cs0b[j & 3]) * ksc;
        float c1f = (j < 4 ? cs1a[j & 3] : cs1b[j & 3]) * ksc;
        oP[j] = (bf16_t)(p0 * p1);
        o1[j] = (bf16_t)(p0 * c1f);
        o2[j] = (bf16_t)(p1 * c0f);
      }
      *(bf16x8*)&sm.sV[0][grp][cb] = oP;
      *(bf16x8*)&sm.sV[1][grp][cb] = o1;
      *(bf16x8*)&sm.sV[2][grp][cb] = o2;
    }
  }
  __syncthreads();

  // ---- MFMA phase ----
  int w = tid >> 6, lane = tid & 63, quad = lane >> 4, lr = lane & 15;
  f32x4 accP[2][2] = {};   // vp@A0 (shared by both outputs)
  f32x4 acc01[2][2] = {};  // v0@A1 + v1@A2  (-> out0)
  f32x4 acc10[2][2] = {};  // v1@A1 + v0@A2  (-> out1)

#pragma unroll
  for (int ks = 0; ks < 4; ++ks) {
    bf16x8 va[2][3];
#pragma unroll
    for (int mt = 0; mt < 2; ++mt)
#pragma unroll
      for (int m = 0; m < 3; ++m)
        va[mt][m] = *(const bf16x8*)&sm.sV[m][mt * 16 + lr][ks * 32 + quad * 8];
    bf16x8 vb[3][2];
#pragma unroll
    for (int m = 0; m < 3; ++m)
#pragma unroll
      for (int ntl = 0; ntl < 2; ++ntl) {
        int nt = w * 2 + ntl;
        vb[m][ntl] = *(const bf16x8*)(A_swz + m * 16384 + (((nt * 4 + ks) * 64) + lane) * 8);
      }
#pragma unroll
    for (int mt = 0; mt < 2; ++mt)
#pragma unroll
      for (int ntl = 0; ntl < 2; ++ntl) {
        accP[mt][ntl]  = __builtin_amdgcn_mfma_f32_16x16x32_bf16(va[mt][0], vb[0][ntl], accP[mt][ntl], 0, 0, 0);
        acc01[mt][ntl] = __builtin_amdgcn_mfma_f32_16x16x32_bf16(va[mt][1], vb[1][ntl], acc01[mt][ntl], 0, 0, 0);
        acc01[mt][ntl] = __builtin_amdgcn_mfma_f32_16x16x32_bf16(va[mt][2], vb[2][ntl], acc01[mt][ntl], 0, 0, 0);
        acc10[mt][ntl] = __builtin_amdgcn_mfma_f32_16x16x32_bf16(va[mt][2], vb[1][ntl], acc10[mt][ntl], 0, 0, 0);
        acc10[mt][ntl] = __builtin_amdgcn_mfma_f32_16x16x32_bf16(va[mt][1], vb[2][ntl], acc10[mt][ntl], 0, 0, 0);
      }
  }
  __syncthreads();   // everyone done reading sV before aliasing as so

  // ---- stage C tiles to LDS (C/D: col=lane&15(+tiles), row=quad*4+reg) ----
#pragma unroll
  for (int ntl = 0; ntl < 2; ++ntl) {
    int col = w * 32 + ntl * 16 + lr;
#pragma unroll
    for (int mt = 0; mt < 2; ++mt)
#pragma unroll
      for (int rg = 0; rg < 4; ++rg) {
        int row = mt * 16 + quad * 4 + rg;
        if (row < 25) {
          sm.so[0][row][col] = accP[mt][ntl][rg] + acc01[mt][ntl][rg];
          sm.so[1][row][col] = accP[mt][ntl][rg] + acc10[mt][ntl][rg];
        }
      }
  }
  __syncthreads();

  // ---- coalesced nontemporal write-out, adding g (bias already folded) ----
  float* o0 = out + (size_t)n * 3200;
  float* o1 = out + (size_t)NPTS * 3200 + (size_t)n * 3200;
  const float* g0 = g + (size_t)n * 128;
  const float* g1 = g + (size_t)(NPTS + n) * 128;
  for (int i = tid; i < 800; i += 256) {
    int f = i * 4, r = f >> 7, c = f & 127;
    f32x4 gv0 = *(const f32x4*)(g0 + c);
    f32x4 gv1 = *(const f32x4*)(g1 + c);
    f32x4 v0 = *(const f32x4*)&sm.so[0][r][c];
    f32x4 v1 = *(const f32x4*)&sm.so[1][r][c];
    __builtin_nontemporal_store(v0 + gv0, (f32x4*)(o0 + f));
    __builtin_nontemporal_store(v1 + gv1, (f32x4*)(o1 + f));
  }
}

// ---------------------------------------------------------------------------
// Fallback (ws too small for ftr+g): round-3 structure, direct f32 gather.
// ---------------------------------------------------------------------------
__global__ __launch_bounds__(256) void ctx_mean_f32_kernel(
    const float* __restrict__ f0, const float* __restrict__ f1,
    float* __restrict__ ctxs) {
  int id = blockIdx.x;
  const float* src = (id < 256 ? f0 : f1) + (size_t)(id & 255) * HW;
  float s = 0.f;
  for (int i = threadIdx.x; i < HW; i += 256) s += src[i];
  for (int off = 32; off > 0; off >>= 1) s += __shfl_down(s, off, 64);
  __shared__ float part[4];
  if ((threadIdx.x & 63) == 0) part[threadIdx.x >> 6] = s;
  __syncthreads();
  if (threadIdx.x == 0) ctxs[id] = part[0] + part[1] + part[2] + part[3];
}

__global__ __launch_bounds__(256, 4) void main_fallback_kernel(
    const float* __restrict__ f0, const float* __restrict__ f1,
    const float* __restrict__ fc0, const float* __restrict__ fc1,
    const int* __restrict__ b_ids, const int* __restrict__ i_ids,
    const int* __restrict__ j_ids, const int* __restrict__ w0c_p,
    const int* __restrict__ w1c_p, const float* __restrict__ ctxs,
    const float* __restrict__ bias_all, const bf16_t* __restrict__ A_swz,
    const bf16_t* __restrict__ Dm, float* __restrict__ out) {
  __shared__ __align__(16) bf16_t sV[3][32][PAD];
  __shared__ float sg[2][128];
  int n = blockIdx.x;
  int tid = threadIdx.x;
  int b = b_ids[n], ii = i_ids[n], jj = j_ids[n];
  int w0c = w0c_p[0], w1c = w1c_p[0];
  int x0 = min((ii % w0c) * 2, WF - 1), y0 = min((ii / w0c) * 2, HF - 1);
  int x1 = min((jj % w1c) * 2, WF - 1), y1 = min((jj / w1c) * 2, HF - 1);
  const float ksc = INV_S / (float)HW;
  int c = tid & 127, kh = tid >> 7;
  float cs0 = ctxs[b * 128 + c] * ksc;
  float cs1 = ctxs[256 + b * 128 + c] * ksc;
  const float* f0b = f0 + (size_t)(b * 128 + c) * HW;
  const float* f1b = f1 + (size_t)(b * 128 + c) * HW;
  for (int k = kh; k < 32; k += 2) {
    float p0 = 0.f, p1 = 0.f;
    if (k < 25) {
      int dy = k / 5 - 2, dx = k % 5 - 2;
      int ya = y0 + dy, xa = x0 + dx;
      if (ya >= 0 && ya < HF && xa >= 0 && xa < WF) p0 = f0b[ya * WF + xa];
      int yb = y1 + dy, xb = x1 + dx;
      if (yb >= 0 && yb < HF && xb >= 0 && xb < WF) p1 = f1b[yb * WF + xb];
    }
    sV[0][k][c] = (bf16_t)(p0 * p1);
    sV[1][k][c] = (bf16_t)(p0 * cs1);
    sV[2][k][c] = (bf16_t)(p1 * cs0);
  }
  {
    int h = tid >> 7, col = tid & 127;
    const float* fcrow = h ? fc1 + ((size_t)b * LC + jj) * D_C
                           : fc0 + ((size_t)b * LC + ii) * D_C;
    float acc = 0.f;
#pragma unroll 8
    for (int t = 0; t < D_C; ++t) acc += fcrow[t] * (float)Dm[t * 128 + col];
    sg[h][col] = acc;
  }
  __syncthreads();
  int w = tid >> 6, lane = tid & 63, quad = lane >> 4, lr = lane & 15;
  f32x4 accP[2][2] = {}, acc01[2][2] = {}, acc10[2][2] = {};
#pragma unroll
  for (int ks = 0; ks < 4; ++ks) {
    bf16x8 va[2][3];
#pragma unroll
    for (int mt = 0; mt < 2; ++mt)
#pragma unroll
      for (int m = 0; m < 3; ++m)
        va[mt][m] = *(const bf16x8*)&sV[m][mt * 16 + lr][ks * 32 + quad * 8];
    bf16x8 vb[3][2];
#pragma unroll
    for (int m = 0; m < 3; ++m)
#pragma unroll
      for (int ntl = 0; ntl < 2; ++ntl) {
        int nt = w * 2 + ntl;
        vb[m][ntl] = *(const bf16x8*)(A_swz + m * 16384 + (((nt * 4 + ks) * 64) + lane) * 8);
      }
#pragma unroll
    for (int mt = 0; mt < 2; ++mt)
#pragma unroll
      for (int ntl = 0; ntl < 2; ++ntl) {
        accP[mt][ntl]  = __builtin_amdgcn_mfma_f32_16x16x32_bf16(va[mt][0], vb[0][ntl], accP[mt][ntl], 0, 0, 0);
        acc01[mt][ntl] = __builtin_amdgcn_mfma_f32_16x16x32_bf16(va[mt][1], vb[1][ntl], acc01[mt][ntl], 0, 0, 0);
        acc01[mt][ntl] = __builtin_amdgcn_mfma_f32_16x16x32_bf16(va[mt][2], vb[2][ntl], acc01[mt][ntl], 0, 0, 0);
        acc10[mt][ntl] = __builtin_amdgcn_mfma_f32_16x16x32_bf16(va[mt][2], vb[1][ntl], acc10[mt][ntl], 0, 0, 0);
        acc10[mt][ntl] = __builtin_amdgcn_mfma_f32_16x16x32_bf16(va[mt][1], vb[2][ntl], acc10[mt][ntl], 0, 0, 0);
      }
  }
#pragma unroll
  for (int ntl = 0; ntl < 2; ++ntl) {
    int col = w * 32 + ntl * 16 + lr;
    float bg = bias_all[col];
    float gg0 = sg[0][col] + bg, gg1 = sg[1][col] + bg;
#pragma unroll
    for (int mt = 0; mt < 2; ++mt)
#pragma unroll
      for (int rg = 0; rg < 4; ++rg) {
        int row = mt * 16 + quad * 4 + rg;
        if (row < 25) {
          size_t o = ((size_t)n * 25 + row) * 128 + col;
          out[o] = accP[mt][ntl][rg] + acc01[mt][ntl][rg] + gg0;
          out[(size_t)NPTS * 25 * 128 + o] = accP[mt][ntl][rg] + acc10[mt][ntl][rg] + gg1;
        }
      }
  }
}

// ---------------------------------------------------------------------------
extern "C" void kernel_launch(void* const* d_in, const int* in_sizes, int n_in,
                              void* d_out, int out_size, void* d_ws, size_t ws_size,
                              hipStream_t stream) {
  const float* f0     = (const float*)d_in[0];
  const float* f1     = (const float*)d_in[1];
  const float* fc0    = (const float*)d_in[2];
  const float* fc1    = (const float*)d_in[3];
  const float* corr_w = (const float*)d_in[4];
  const float* corr_b = (const float*)d_in[5];
  const float* dp_w   = (const float*)d_in[6];
  const float* dp_b   = (const float*)d_in[7];
  const float* mg_w   = (const float*)d_in[8];
  const float* mg_b   = (const float*)d_in[9];
  const int* b_ids    = (const int*)d_in[10];
  const int* i_ids    = (const int*)d_in[11];
  const int* j_ids    = (const int*)d_in[12];
  const int* w0c      = (const int*)d_in[13];
  const int* w1c      = (const int*)d_in[14];

  char* ws = (char*)d_ws;
  float*  ctxs     = (float*)(ws);
  float*  bias_all = (float*)(ws + 4096);
  bf16_t* A_swz    = (bf16_t*)(ws + 8192);
  bf16_t* Dm       = (bf16_t*)(ws + 106496);
  bf16_t* ftr      = (bf16_t*)(ws + FTR_OFF);
  float*  g        = (float*)(ws + G_OFF);
  int fast = (ws_size >= G_OFF + G_BYTES) ? 1 : 0;

  prep_kernel<<<641, 128, 0, stream>>>(corr_w, corr_b, dp_w, dp_b, mg_w, mg_b,
                                       A_swz, Dm, bias_all);
  if (fast) {
    hipMemsetAsync(ctxs, 0, 2048, stream);
    transpose_kernel<<<2704, 256, 0, stream>>>(f0, f1, ftr, ctxs);
    g_kernel<<<625, 128, 0, stream>>>(fc0, fc1, b_ids, i_ids, j_ids, Dm,
                                      bias_all, g);
    main_kernel<<<NPTS, 256, 0, stream>>>(ftr, b_ids, i_ids, j_ids, w0c, w1c,
                                          ctxs, A_swz, g, (float*)d_out);
  } else {
    ctx_mean_f32_kernel<<<512, 256, 0, stream>>>(f0, f1, ctxs);
    main_fallback_kernel<<<NPTS, 256, 0, stream>>>(f0, f1, fc0, fc1, b_ids,
                                                   i_ids, j_ids, w0c, w1c, ctxs,
                                                   bias_all, A_swz, Dm,
                                                   (float*)d_out);
  }
}